// Round 1
// baseline (2556.314 us; speedup 1.0000x reference)
//
#include <hip/hip_runtime.h>
#include <math.h>

typedef __attribute__((ext_vector_type(8))) short bf16x8;
typedef __attribute__((ext_vector_type(4))) float f32x4;

#define DEVI __device__ __forceinline__

DEVI short f2bf(float f) {
  unsigned u = __builtin_bit_cast(unsigned, f);
  return (short)((u + 0x7fffu + ((u >> 16) & 1u)) >> 16);
}

DEVI float silu_f(float v) { return v / (1.0f + expf(-v)); }

DEVI void async16(const void* g, void* l) {
  __builtin_amdgcn_global_load_lds(
      (const __attribute__((address_space(1))) void*)g,
      (__attribute__((address_space(3))) void*)l, 16, 0, 0);
}

// ---------------- GEMM: out(M,N) from A(M,K)bf16 @ BT(N,K)bf16 + bias ----------
// MODE 0: out_f32  = v
// MODE 1: out_f32  = aux * silu(v)
// MODE 2: out_bf16 = aux * silu(v)
// MODE 3: out_f32 += v * silu(aux)
// MODE 4: out_f32 += v
template <int MODE>
__global__ __launch_bounds__(256) void gemm_k(const short* __restrict__ A,
                                              const short* __restrict__ BT,
                                              const float* __restrict__ bias,
                                              const float* __restrict__ aux,
                                              void* __restrict__ outp,
                                              int N, int K) {
  __shared__ __align__(16) short lA[128 * 32];
  __shared__ __align__(16) short lB[128 * 32];
  const int row0 = blockIdx.y << 7, col0 = blockIdx.x << 7;
  const int t = threadIdx.x, w = t >> 6, lane = t & 63;
  const int wr = w >> 1, wc = w & 1;
  f32x4 acc[4][4] = {};

  // staging: LDS linear [row][k], row stride 64B; wave-uniform LDS base + lane*16
  const int srow = (w << 4) + (lane >> 2);
  const int scolb = (lane & 3) << 4;
  const char* gA = (const char*)A + ((size_t)(row0 + srow) * K) * 2 + scolb;
  const char* gB = (const char*)BT + ((size_t)(col0 + srow) * K) * 2 + scolb;
  const size_t rstep = (size_t)K << 7;  // 64 rows * K * 2B
  char* lAw = (char*)lA + (w << 10);
  char* lBw = (char*)lB + (w << 10);
  const int lr = lane & 15, lkb = (lane >> 4) << 4;

  for (int k0 = 0; k0 < K; k0 += 32) {
    __syncthreads();
    async16(gA, lAw);
    async16(gA + rstep, lAw + 4096);
    async16(gB, lBw);
    async16(gB + rstep, lBw + 4096);
    gA += 64; gB += 64;
    __syncthreads();
    bf16x8 af[4], bfr[4];
#pragma unroll
    for (int m = 0; m < 4; ++m)
      af[m] = *(const bf16x8*)((const char*)lA + (((wr << 6) + (m << 4) + lr) << 6) + lkb);
#pragma unroll
    for (int n = 0; n < 4; ++n)
      bfr[n] = *(const bf16x8*)((const char*)lB + (((wc << 6) + (n << 4) + lr) << 6) + lkb);
#pragma unroll
    for (int m = 0; m < 4; ++m)
#pragma unroll
      for (int n = 0; n < 4; ++n)
        acc[m][n] = __builtin_amdgcn_mfma_f32_16x16x32_bf16(af[m], bfr[n], acc[m][n], 0, 0, 0);
  }

  // epilogue: C/D layout row = 4*(lane>>4)+i, col = lane&15 (m89-verified)
  const int orow = row0 + (wr << 6) + ((lane >> 4) << 2);
  const int ocol = col0 + (wc << 6) + lr;
#pragma unroll
  for (int m = 0; m < 4; ++m) {
#pragma unroll
    for (int n = 0; n < 4; ++n) {
      const int c = ocol + (n << 4);
      const float bv = bias[c];
#pragma unroll
      for (int i = 0; i < 4; ++i) {
        const int r = orow + (m << 4) + i;
        const size_t idx = (size_t)r * N + c;
        float v = acc[m][n][i] + bv;
        if (MODE == 0) ((float*)outp)[idx] = v;
        else if (MODE == 1) ((float*)outp)[idx] = aux[idx] * silu_f(v);
        else if (MODE == 2) ((short*)outp)[idx] = f2bf(aux[idx] * silu_f(v));
        else if (MODE == 3) ((float*)outp)[idx] += v * silu_f(aux[idx]);
        else if (MODE == 4) ((float*)outp)[idx] += v;
      }
    }
  }
}

// ------------- transpose-convert: W(R,C) fp32 -> WT(C,R) bf16, per blockIdx.z matrix
__global__ __launch_bounds__(256) void transp_k(const float* __restrict__ W,
                                                short* __restrict__ WT,
                                                int R, int C) {
  __shared__ float tile[32][33];
  const size_t moff = (size_t)blockIdx.z * R * C;
  const float* Wp = W + moff;
  short* Tp = WT + moff;
  const int c0 = blockIdx.x << 5, r0 = blockIdx.y << 5;
  const int tx = threadIdx.x, ty = threadIdx.y;
#pragma unroll
  for (int i = 0; i < 4; ++i)
    tile[ty + 8 * i][tx] = Wp[(size_t)(r0 + ty + 8 * i) * C + (c0 + tx)];
  __syncthreads();
#pragma unroll
  for (int i = 0; i < 4; ++i)
    Tp[(size_t)(c0 + ty + 8 * i) * R + (r0 + tx)] = f2bf(tile[tx][ty + 8 * i]);
}

// ------------- embedding with max_norm=1 renorm -> fp32 residual stream
__global__ __launch_bounds__(256) void embed_k(const int* __restrict__ tok,
                                               const float* __restrict__ emb,
                                               float* __restrict__ x) {
  const int row = blockIdx.x, t = threadIdx.x, w = t >> 6, lane = t & 63;
  const int token = tok[row];
  float4 v = ((const float4*)(emb + (size_t)token * 1024))[t];
  float ss = v.x * v.x + v.y * v.y + v.z * v.z + v.w * v.w;
#pragma unroll
  for (int off = 32; off; off >>= 1) ss += __shfl_xor(ss, off, 64);
  __shared__ float red[4];
  if (lane == 0) red[w] = ss;
  __syncthreads();
  const float nrm = sqrtf(red[0] + red[1] + red[2] + red[3]);
  const float sc = fminf(1.0f, 1.0f / fmaxf(nrm, 1e-7f));
  v.x *= sc; v.y *= sc; v.z *= sc; v.w *= sc;
  ((float4*)(x + (size_t)row * 1024))[t] = v;
}

// ------------- RMSNorm row kernel: fp32 in -> bf16 out
__global__ __launch_bounds__(256) void rms_k(const float* __restrict__ x,
                                             const float* __restrict__ g,
                                             short* __restrict__ o) {
  const int row = blockIdx.x, t = threadIdx.x, w = t >> 6, lane = t & 63;
  float4 v = ((const float4*)(x + (size_t)row * 1024))[t];
  float ss = v.x * v.x + v.y * v.y + v.z * v.z + v.w * v.w;
#pragma unroll
  for (int off = 32; off; off >>= 1) ss += __shfl_xor(ss, off, 64);
  __shared__ float red[4];
  if (lane == 0) red[w] = ss;
  __syncthreads();
  const float sc = rsqrtf((red[0] + red[1] + red[2] + red[3]) * (1.0f / 1024.0f) + 1e-6f);
  float4 gv = ((const float4*)g)[t];
  short4 ov = make_short4(f2bf(v.x * sc * gv.x), f2bf(v.y * sc * gv.y),
                          f2bf(v.z * sc * gv.z), f2bf(v.w * sc * gv.w));
  *(short4*)(o + (size_t)row * 1024 + 4 * t) = ov;
}

// ------------- final LayerNorm: fp32 in -> bf16 out
__global__ __launch_bounds__(256) void ln_k(const float* __restrict__ x,
                                            const float* __restrict__ lw,
                                            const float* __restrict__ lb,
                                            short* __restrict__ o) {
  const int row = blockIdx.x, t = threadIdx.x, w = t >> 6, lane = t & 63;
  float4 v = ((const float4*)(x + (size_t)row * 1024))[t];
  float s1 = v.x + v.y + v.z + v.w;
  float s2 = v.x * v.x + v.y * v.y + v.z * v.z + v.w * v.w;
#pragma unroll
  for (int off = 32; off; off >>= 1) {
    s1 += __shfl_xor(s1, off, 64);
    s2 += __shfl_xor(s2, off, 64);
  }
  __shared__ float red[8];
  if (lane == 0) { red[w] = s1; red[4 + w] = s2; }
  __syncthreads();
  const float mu = (red[0] + red[1] + red[2] + red[3]) * (1.0f / 1024.0f);
  const float ex2 = (red[4] + red[5] + red[6] + red[7]) * (1.0f / 1024.0f);
  const float rs = rsqrtf(ex2 - mu * mu + 1e-5f);
  float4 wv = ((const float4*)lw)[t];
  float4 bv = ((const float4*)lb)[t];
  short4 ov = make_short4(f2bf((v.x - mu) * rs * wv.x + bv.x),
                          f2bf((v.y - mu) * rs * wv.y + bv.y),
                          f2bf((v.z - mu) * rs * wv.z + bv.z),
                          f2bf((v.w - mu) * rs * wv.w + bv.w));
  *(short4*)(o + (size_t)row * 1024 + 4 * t) = ov;
}

// ------------- SConv as a first-order complex IIR, wave-parallel chunked scan.
// h[t] = Re( scan_t ) + Re( lc * decay^(t+1) ),  scan_t = decay*scan_{t-1} + z[t]
// One wave per (b,d) channel; lane j owns timesteps [32j, 32j+32).
__global__ __launch_bounds__(256) void scan_k(const float* __restrict__ z,
                                              float* __restrict__ h,
                                              const float* __restrict__ lcre,
                                              const float* __restrict__ lcim) {
  const int w = threadIdx.x >> 6, lane = threadIdx.x & 63;
  const int ch = (blockIdx.x << 2) + w;
  const int b = ch >> 10, d = ch & 1023;
  const float ang = powf(1e-3f, (float)d * (1.0f / 1023.0f));
  float sn, cs;
  sincosf(ang, &sn, &cs);
  const float mag = expf(1e-5f);
  const float dr = mag * cs, di = mag * sn;  // decay = exp(1e-5 + i*ang)
  // A32 = decay^32 by 5 squarings
  float ar = dr, ai = di;
#pragma unroll
  for (int q = 0; q < 5; ++q) { float nr = ar * ar - ai * ai; ai = 2.0f * ar * ai; ar = nr; }
  const float* zc = z + ((size_t)(b * 2048 + (lane << 5)) << 10) + d;
  // pass 1: chunk-local end state E (seeded 0)
  float sr = 0.0f, si = 0.0f;
  for (int k = 0; k < 32; ++k) {
    float zv = zc[(size_t)k << 10];
    float nr = dr * sr - di * si + zv;
    si = dr * si + di * sr;
    sr = nr;
  }
  // wave inclusive scan of affine ops (P,S): new = cur ∘ other
  float Pr = ar, Pi = ai, Sr = sr, Si = si;
#pragma unroll
  for (int off = 1; off < 64; off <<= 1) {
    float Por = __shfl_up(Pr, (unsigned)off, 64), Poi = __shfl_up(Pi, (unsigned)off, 64);
    float Sor = __shfl_up(Sr, (unsigned)off, 64), Soi = __shfl_up(Si, (unsigned)off, 64);
    if (lane >= off) {
      float nSr = Pr * Sor - Pi * Soi + Sr;
      float nSi = Pr * Soi + Pi * Sor + Si;
      float nPr = Pr * Por - Pi * Poi;
      float nPi = Pr * Poi + Pi * Por;
      Sr = nSr; Si = nSi; Pr = nPr; Pi = nPi;
    }
  }
  float S0r = __shfl_up(Sr, 1u, 64), S0i = __shfl_up(Si, 1u, 64);
  if (lane == 0) { S0r = 0.0f; S0i = 0.0f; }
  // W = decay^(32*lane+1) = decay * (A32)^lane  (binary pow on lane)
  float wr_ = 1.0f, wi_ = 0.0f, br = ar, bi = ai;
  int e = lane;
  while (e) {
    if (e & 1) { float nr = wr_ * br - wi_ * bi; wi_ = wr_ * bi + wi_ * br; wr_ = nr; }
    float nb = br * br - bi * bi; bi = 2.0f * br * bi; br = nb;
    e >>= 1;
  }
  { float nr = wr_ * dr - wi_ * di; wi_ = wr_ * di + wi_ * dr; wr_ = nr; }
  const float lr_ = lcre[d], li_ = lcim[d];
  // pass 2: rerun chunk seeded with exclusive prefix, emit h.real + lc-term
  float s_r = S0r, s_i = S0i;
  float* hc = h + ((size_t)(b * 2048 + (lane << 5)) << 10) + d;
  for (int k = 0; k < 32; ++k) {
    float zv = zc[(size_t)k << 10];
    float nr = dr * s_r - di * s_i + zv;
    s_i = dr * s_i + di * s_r;
    s_r = nr;
    hc[(size_t)k << 10] = s_r + lr_ * wr_ - li_ * wi_;
    float nw = wr_ * dr - wi_ * di;
    wi_ = wr_ * di + wi_ * dr;
    wr_ = nw;
  }
}

extern "C" void kernel_launch(void* const* d_in, const int* in_sizes, int n_in,
                              void* d_out, int out_size, void* d_ws, size_t ws_size,
                              hipStream_t stream) {
  const int* tokens = (const int*)d_in[0];
  const float* emb = (const float*)d_in[1];
  const float* Wz = (const float*)d_in[2];
  const float* bz = (const float*)d_in[3];
  const float* Wza = (const float*)d_in[4];
  const float* bza = (const float*)d_in[5];
  const float* Wy = (const float*)d_in[6];
  const float* by = (const float*)d_in[7];
  const float* Wya = (const float*)d_in[8];
  const float* bya = (const float*)d_in[9];
  const float* lc_re = (const float*)d_in[10];
  const float* lc_im = (const float*)d_in[11];
  const float* g_in = (const float*)d_in[12];
  const float* g_sc = (const float*)d_in[13];
  const float* g_ffn = (const float*)d_in[14];
  const float* Wf = (const float*)d_in[15];
  const float* bf = (const float*)d_in[16];
  const float* Wfa = (const float*)d_in[17];
  const float* bfa = (const float*)d_in[18];
  const float* Wfo = (const float*)d_in[19];
  const float* bfo = (const float*)d_in[20];
  const float* ln_w = (const float*)d_in[21];
  const float* ln_b = (const float*)d_in[22];
  const float* Wout = (const float*)d_in[23];
  const float* bout = (const float*)d_in[24];

  char* p = (char*)d_ws;
  float* xb = (float*)p;   p += (size_t)4096 * 1024 * 4;
  float* buf1 = (float*)p; p += (size_t)4096 * 1024 * 4;
  float* buf2 = (float*)p; p += (size_t)4096 * 1024 * 4;
  float* fbuf = (float*)p; p += (size_t)4096 * 4096 * 4;
  short* xnb = (short*)p;  p += (size_t)4096 * 1024 * 2;
  short* hnb = (short*)p;  p += (size_t)4096 * 1024 * 2;
  short* gb = (short*)p;   p += (size_t)4096 * 4096 * 2;
  short* WzT = (short*)p;  p += (size_t)4 * 1024 * 1024 * 2;
  short* WzaT = (short*)p; p += (size_t)4 * 1024 * 1024 * 2;
  short* WyT = (short*)p;  p += (size_t)4 * 1024 * 1024 * 2;
  short* WyaT = (short*)p; p += (size_t)4 * 1024 * 1024 * 2;
  short* WfT = (short*)p;  p += (size_t)4 * 1024 * 4096 * 2;
  short* WfaT = (short*)p; p += (size_t)4 * 1024 * 4096 * 2;
  short* WfoT = (short*)p; p += (size_t)4 * 1024 * 4096 * 2;
  short* WoutT = (short*)p; p += (size_t)32000 * 1024 * 2;

  const dim3 tb(32, 8);
  transp_k<<<dim3(32, 32, 4), tb, 0, stream>>>(Wz, WzT, 1024, 1024);
  transp_k<<<dim3(32, 32, 4), tb, 0, stream>>>(Wza, WzaT, 1024, 1024);
  transp_k<<<dim3(32, 32, 4), tb, 0, stream>>>(Wy, WyT, 1024, 1024);
  transp_k<<<dim3(32, 32, 4), tb, 0, stream>>>(Wya, WyaT, 1024, 1024);
  transp_k<<<dim3(128, 32, 4), tb, 0, stream>>>(Wf, WfT, 1024, 4096);
  transp_k<<<dim3(128, 32, 4), tb, 0, stream>>>(Wfa, WfaT, 1024, 4096);
  transp_k<<<dim3(32, 128, 4), tb, 0, stream>>>(Wfo, WfoT, 4096, 1024);
  transp_k<<<dim3(1000, 32, 1), tb, 0, stream>>>(Wout, WoutT, 1024, 32000);

  embed_k<<<4096, 256, 0, stream>>>(tokens, emb, xb);

  for (int i = 0; i < 4; ++i) {
    const size_t dd = (size_t)i * 1024 * 1024;
    const size_t dv = (size_t)i * 1024;
    const size_t dw = (size_t)i * 1024 * 4096;
    const size_t df = (size_t)i * 4096;
    rms_k<<<4096, 256, 0, stream>>>(xb, g_sc + dv, xnb);
    // zpre = xn@Wz+bz
    gemm_k<0><<<dim3(8, 32), 256, 0, stream>>>(xnb, WzT + dd, bz + dv, nullptr, buf1, 1024, 1024);
    // z = zpre * silu(xn@Wza+bza)
    gemm_k<1><<<dim3(8, 32), 256, 0, stream>>>(xnb, WzaT + dd, bza + dv, buf1, buf2, 1024, 1024);
    // h = IIR scan of z + lc*decay^(t+1)
    scan_k<<<512, 256, 0, stream>>>(buf2, buf1, lc_re + dv, lc_im + dv);
    rms_k<<<4096, 256, 0, stream>>>(buf1, g_in + dv, hnb);
    // yapre = xn@Wya+bya
    gemm_k<0><<<dim3(8, 32), 256, 0, stream>>>(xnb, WyaT + dd, bya + dv, nullptr, buf2, 1024, 1024);
    // x += (hn@Wy+by) * silu(yapre)
    gemm_k<3><<<dim3(8, 32), 256, 0, stream>>>(hnb, WyT + dd, by + dv, buf2, xb, 1024, 1024);
    rms_k<<<4096, 256, 0, stream>>>(xb, g_ffn + dv, xnb);
    // f1 = xn@Wf+bf
    gemm_k<0><<<dim3(32, 32), 256, 0, stream>>>(xnb, WfT + dw, bf + df, nullptr, fbuf, 4096, 1024);
    // g = f1 * silu(xn@Wfa+bfa)  (bf16)
    gemm_k<2><<<dim3(32, 32), 256, 0, stream>>>(xnb, WfaT + dw, bfa + df, fbuf, gb, 4096, 1024);
    // x += g@Wfo + bfo
    gemm_k<4><<<dim3(8, 32), 256, 0, stream>>>(gb, WfoT + dw, bfo + dv, nullptr, xb, 1024, 4096);
  }

  ln_k<<<4096, 256, 0, stream>>>(xb, ln_w, ln_b, xnb);
  gemm_k<0><<<dim3(250, 32), 256, 0, stream>>>(xnb, WoutT, bout, nullptr, (float*)d_out, 32000, 1024);

  (void)in_sizes; (void)n_in; (void)out_size; (void)ws_size;
}